// Round 5
// baseline (118.009 us; speedup 1.0000x reference)
//
#include <hip/hip_runtime.h>

#define SMOOTH 1e-5f

typedef float  floatx4 __attribute__((ext_vector_type(4)));

// ws[scale][img][5] = {C, S, inter, z_sum, p_sum}

__device__ __forceinline__ float wave_reduce(float v) {
#pragma unroll
    for (int off = 32; off; off >>= 1) v += __shfl_down(v, off, 64);
    return v;
}

__device__ __forceinline__ float sigmoidf(float x) {
    return 1.f / (1.f + __expf(-x));
}

// 2048 blocks = 32 images x 64 tiles (8x8 tiles of 64x64 full-res px).
// XCD swizzle: img = blk%8 + 8*(blk/512) keeps one image's tiles on one XCD.
// Phase-overlapped: logits prefetched into registers BEFORE target staging so
// the pre-barrier vmcnt drain covers max(staging, logits), not their sum.
__global__ __launch_bounds__(256) void bdou_fused(
    const float* __restrict__ l0, const float* __restrict__ l1,
    const float* __restrict__ l2, const int* __restrict__ tgt,
    float* __restrict__ ws)
{
    __shared__ unsigned Tw[72 * 20];          // 72 rows x 20 words (80B), cols 0..17 used
    __shared__ float red[4][15];

    const int blk  = blockIdx.x;
    const int img  = (blk & 7) + 8 * (blk >> 9);
    const int tile = (blk >> 3) & 63;
    const int ty0  = (tile >> 3) * 64;
    const int tx0  = (tile & 7) * 64;
    const int tid  = threadIdx.x;

    const int* __restrict__ timg = tgt + (size_t)img * (512 * 512);

    // ---- prefetch ALL logits into registers (independent of LDS) ----
    const float* __restrict__ l0img = l0 + (size_t)img * (512 * 512);
    floatx4 lg0[4];
#pragma unroll
    for (int it = 0; it < 4; ++it) {
        int p  = tid * 4 + it * 1024;
        int ly = p >> 6, lx = p & 63;
        lg0[it] = __builtin_nontemporal_load(
            reinterpret_cast<const floatx4*>(l0img + (size_t)(ty0 + ly) * 512 + tx0 + lx));
    }
    const int dY1 = tid >> 3, dX1 = (tid & 7) * 4;
    floatx4 lg1 = __builtin_nontemporal_load(reinterpret_cast<const floatx4*>(
        l1 + (size_t)img * 65536 + (size_t)(ty0 / 2 + dY1) * 256 + tx0 / 2 + dX1));
    const int dY2 = tid >> 4, dX2 = tid & 15;
    float lg2 = __builtin_nontemporal_load(
        l2 + (size_t)img * 16384 + (size_t)(ty0 / 4 + dY2) * 128 + tx0 / 4 + dX2);

    // ---- stage target halo tile: 72 rows x 18 int4 = 1296 jobs ----
    for (int j = tid; j < 1296; j += 256) {
        int r = j / 18, c = j - r * 18;
        int gy = ty0 - 4 + r;
        int gx = tx0 - 4 + c * 4;
        unsigned w = 0;
        if ((unsigned)gy < 512u && (unsigned)gx < 512u) {  // gx=-4 / 512 fully OOB
            int4 v = *reinterpret_cast<const int4*>(timg + (size_t)gy * 512 + gx);
            w = (v.x != 0 ? 1u : 0) | (v.y != 0 ? 1u << 8 : 0) |
                (v.z != 0 ? 1u << 16 : 0) | (v.w != 0 ? 1u << 24 : 0);
        }
        Tw[r * 20 + c] = w;
    }
    __syncthreads();

    int   cC0 = 0, cS0 = 0, cC1 = 0, cS1 = 0, cC2 = 0, cS2 = 0;
    float aI0 = 0.f, aZ0 = 0.f, aP0 = 0.f;
    float aI1 = 0.f, aZ1 = 0.f, aP1 = 0.f;
    float aI2 = 0.f, aZ2 = 0.f, aP2 = 0.f;

    // ---- scale 0: 64x64 px, 16 px/thread ----
#pragma unroll
    for (int it = 0; it < 4; ++it) {
        int p  = tid * 4 + it * 1024;
        int ly = p >> 6, lx = p & 63;
        int wb = lx >> 2;
        unsigned cw = Tw[(ly + 4) * 20 + wb + 1];
        unsigned lw = Tw[(ly + 4) * 20 + wb];
        unsigned rw = Tw[(ly + 4) * 20 + wb + 2];
        unsigned uw = Tw[(ly + 3) * 20 + wb + 1];
        unsigned dw = Tw[(ly + 5) * 20 + wb + 1];
        float pr[4] = {sigmoidf(lg0[it].x), sigmoidf(lg0[it].y),
                       sigmoidf(lg0[it].z), sigmoidf(lg0[it].w)};
#pragma unroll
        for (int j = 0; j < 4; ++j) {
            unsigned t = (cw >> (8 * j)) & 1u;
            unsigned u = (uw >> (8 * j)) & 1u;
            unsigned d = (dw >> (8 * j)) & 1u;
            unsigned lf = (j == 0) ? (lw >> 24) & 1u : (cw >> (8 * (j - 1))) & 1u;
            unsigned rt = (j == 3) ? rw & 1u : (cw >> (8 * (j + 1))) & 1u;
            cS0 += (int)t;
            cC0 += (int)(t & ~(u & d & lf & rt));
            aI0 += pr[j] * (float)t;
            aZ0 += pr[j] * pr[j];
            aP0 += pr[j];
        }
    }

    // ---- scale 1: 32x32 ds px in this tile, 4 px/thread ----
    {
        int fy = dY1 * 2, fx = (tid & 7) * 8;         // full-res local coords
        int rb = (fy + 4) * 20 + (fx >> 2);
        unsigned cwv[4] = {Tw[rb], Tw[rb + 1], Tw[rb + 2], Tw[rb + 3]};
        unsigned uwv[2] = {Tw[rb - 40 + 1], Tw[rb - 40 + 2]};
        unsigned dwv[2] = {Tw[rb + 40 + 1], Tw[rb + 40 + 2]};
        float pr[4] = {sigmoidf(lg1.x), sigmoidf(lg1.y), sigmoidf(lg1.z), sigmoidf(lg1.w)};
#pragma unroll
        for (int j = 0; j < 4; ++j) {
            // halfword index within 4-word window: center=2+j, left=1+j, right=3+j
            unsigned t  = (cwv[(2 + j) >> 1] >> (16 * ((2 + j) & 1))) & 1u;
            unsigned lf = (cwv[(1 + j) >> 1] >> (16 * ((1 + j) & 1))) & 1u;
            unsigned rt = (cwv[(3 + j) >> 1] >> (16 * ((3 + j) & 1))) & 1u;
            unsigned u  = (uwv[((2 + j) >> 1) - 1] >> (16 * ((2 + j) & 1))) & 1u;
            unsigned d  = (dwv[((2 + j) >> 1) - 1] >> (16 * ((2 + j) & 1))) & 1u;
            cS1 += (int)t;
            cC1 += (int)(t & ~(u & d & lf & rt));
            aI1 += pr[j] * (float)t;
            aZ1 += pr[j] * pr[j];
            aP1 += pr[j];
        }
    }

    // ---- scale 2: 16x16 ds px in this tile, 1 px/thread ----
    {
        int fy = dY2 * 4, fx = dX2 * 4;
        const unsigned char* Tb = (const unsigned char*)Tw;
        int rc = (fy + 4) * 80 + fx + 4;
        unsigned t  = Tb[rc];
        unsigned u  = Tb[rc - 4 * 80];
        unsigned d  = Tb[rc + 4 * 80];
        unsigned lf = Tb[rc - 4];
        unsigned rt = Tb[rc + 4];
        float pr = sigmoidf(lg2);
        cS2 += (int)t;
        cC2 += (int)(t & ~(u & d & lf & rt));
        aI2 += pr * (float)t;
        aZ2 += pr * pr;
        aP2 += pr;
    }

    // ---- block reduce 15 partials, atomic into ws ----
    float vals[15] = {(float)cC0, (float)cS0, aI0, aZ0, aP0,
                      (float)cC1, (float)cS1, aI1, aZ1, aP1,
                      (float)cC2, (float)cS2, aI2, aZ2, aP2};
#pragma unroll
    for (int k = 0; k < 15; ++k) vals[k] = wave_reduce(vals[k]);
    int wave = tid >> 6, lane = tid & 63;
    if (lane == 0) {
#pragma unroll
        for (int k = 0; k < 15; ++k) red[wave][k] = vals[k];
    }
    __syncthreads();
    if (tid < 15) {
        float s = red[0][tid] + red[1][tid] + red[2][tid] + red[3][tid];
        int sc = tid / 5, k = tid - sc * 5;
        atomicAdd(&ws[(sc * 32 + img) * 5 + k], s);
    }
}

// 128 threads: tid<96 -> one (scale,img) pair each; wave+LDS reduce.
__global__ void bdou_final(const float* __restrict__ ws,
                           const float* __restrict__ valid_mask,
                           float* __restrict__ out)
{
    int tid = threadIdx.x;
    float contrib = 0.f, cpart = 0.f;
    if (tid < 96) {
        int s = tid >> 5, i = tid & 31;
        const float* w = ws + tid * 5;
        float C = w[0], S = w[1], I = w[2], Z = w[3], P = w[4];
        float valid = (valid_mask[i] >= 0.5f) ? 1.f : 0.f;
        float alpha = fminf(2.f * (1.f - (C + SMOOTH) / (S + SMOOTH)) - 1.f, 0.8f);
        float dou = (Z + S - 2.f * I + SMOOTH) /
                    (Z + S - (1.f + alpha) * I + SMOOTH);
        const float wts[3]  = {4.f / 7.f, 2.f / 7.f, 1.f / 7.f};
        const float pixc[3] = {262144.f, 65536.f, 16384.f};
        float per = (S > 0.f) ? dou : (P / pixc[s]);
        contrib = wts[s] * per * valid;
        if (tid < 32) cpart = valid;
    }
    contrib = wave_reduce(contrib);
    cpart   = wave_reduce(cpart);
    __shared__ float sm[2][2];
    int wv = tid >> 6, ln = tid & 63;
    if (ln == 0) { sm[wv][0] = contrib; sm[wv][1] = cpart; }
    __syncthreads();
    if (tid == 0) {
        float tot = sm[0][0] + sm[1][0];
        float cnt = sm[0][1] + sm[1][1];
        out[0] = (cnt > 0.f) ? tot / cnt : 0.f;
    }
}

extern "C" void kernel_launch(void* const* d_in, const int* in_sizes, int n_in,
                              void* d_out, int out_size, void* d_ws, size_t ws_size,
                              hipStream_t stream) {
    const float* l0 = (const float*)d_in[0];
    const float* l1 = (const float*)d_in[1];
    const float* l2 = (const float*)d_in[2];
    const int*   tg = (const int*)d_in[3];
    const float* vm = (const float*)d_in[4];
    float* ws = (float*)d_ws;

    (void)hipMemsetAsync(ws, 0, 3 * 32 * 5 * sizeof(float), stream);
    bdou_fused<<<2048, 256, 0, stream>>>(l0, l1, l2, tg, ws);
    bdou_final<<<1, 128, 0, stream>>>(ws, vm, (float*)d_out);
}